// Round 9
// baseline (535.420 us; speedup 1.0000x reference)
//
#include <hip/hip_runtime.h>
#include <hip/hip_fp16.h>

// ---------------------------------------------------------------------------
// 2-layer GCN via device-built CSR. CSR build = deterministic two-level
// counting sort with per-block histograms (NO global atomics anywhere):
//   k_hist  : per-block LDS hist of its edge range -> hist[b][k]
//   k_scanA : column scan over blocks -> in-place per-block offsets + colsum
//   k_scanB : exclusive scan of colsum -> bstart (bucket bases)
//   k_bin   : LDS cursors = bstart[k]+hist[b][k]; scatter packed
//             (dlow<<18)|src into bbuf (per-block runs contiguous)
//   k_bucket: per-bucket LDS hist+scan -> rp/dinv, clustered scatter -> adj
// Layers (aggregate-first on layer 2; aggregation is linear):
//   h1 = x@W1 (fp16 table); z1 = relu(agg(h1)+b1) (fp16 table);
//   pre = agg(z1) (f32); out = pre@W2 + b2
// fp16 tables: gather row = 32 B, table = 6.4 MB (vs 12.8 f32) -> better
// per-XCD L2 fit, half the miss traffic (round-8: FETCH 348 MB/gather).
// k_bin/k_hist: 512 blocks x 256 thr (round-8's 128 blocks covered only
// half the CUs -> 19% occupancy, latency-bound).
// Bucket = 256 consecutive dst nodes; packing needs n < 2^18 (200000 ok).
// bbuf (25.6 MB) aliases {h1h, z1h, pre} exactly (dead before k_mm1).
// ---------------------------------------------------------------------------

#define TPB 256
#define NBB 512         // bin/hist blocks
#define BINT 256        // threads per bin/hist block

__device__ __forceinline__ int clampi(int v, int n) {
    return v < 0 ? 0 : (v >= n ? n - 1 : v);
}

// --- per-block LDS histogram over contiguous range -----------------------
__global__ __launch_bounds__(BINT) void k_hist(const int* __restrict__ dst,
                                               int E, int n, int nbuck,
                                               int chunk,
                                               int* __restrict__ hist) {
    __shared__ int lh[1024];
    const int b = blockIdx.x;
    const int t = threadIdx.x;
    for (int k = t; k < 1024; k += BINT) lh[k] = 0;
    __syncthreads();
    const int start = b * chunk;
    const int end = min(E, start + chunk);
    for (int i = start + t; i < end; i += BINT)
        atomicAdd(&lh[clampi(dst[i], n) >> 8], 1);
    __syncthreads();
    for (int k = t; k < nbuck; k += BINT) hist[b * nbuck + k] = lh[k];
}

// --- column scan: hist[b][k] -> exclusive prefix over b; colsum[k] -------
__global__ void k_scanA(int* __restrict__ hist, int nbuck, int nbb,
                        int* __restrict__ colsum) {
    int k = blockIdx.x * blockDim.x + threadIdx.x;
    if (k >= nbuck) return;
    int run = 0;
#pragma unroll 4
    for (int b = 0; b < nbb; ++b) {
        int v = hist[b * nbuck + k];
        hist[b * nbuck + k] = run;
        run += v;
    }
    colsum[k] = run;
}

// --- exclusive scan of colsum -> bstart[0..nbuck] ------------------------
__global__ void k_scanB(const int* __restrict__ colsum, int nbuck, int E,
                        int* __restrict__ bstart) {
    __shared__ int s[256];
    const int t = threadIdx.x;
    int loc[4];
    int a = 0;
#pragma unroll
    for (int i = 0; i < 4; ++i) {
        int idx = 4 * t + i;
        loc[i] = (idx < nbuck) ? colsum[idx] : 0;
        a += loc[i];
    }
    s[t] = a;
    __syncthreads();
#pragma unroll
    for (int off = 1; off < 256; off <<= 1) {
        int v = (t >= off) ? s[t - off] : 0;
        __syncthreads();
        s[t] += v;
        __syncthreads();
    }
    int base = s[t] - a;
#pragma unroll
    for (int i = 0; i < 4; ++i) {
        int idx = 4 * t + i;
        if (idx < nbuck) bstart[idx] = base;
        base += loc[i];
    }
    if (t == 255) bstart[nbuck] = E;
}

// --- binning: LDS cursors, LDS atomics only; 2-way independent unroll ----
__global__ __launch_bounds__(BINT) void k_bin(const int* __restrict__ src,
                                              const int* __restrict__ dst,
                                              int E, int n, int nbuck,
                                              int chunk,
                                              const int* __restrict__ hist,
                                              const int* __restrict__ bstart,
                                              int* __restrict__ bbuf) {
    __shared__ int lcur[1024];
    const int b = blockIdx.x;
    const int t = threadIdx.x;
    for (int k = t; k < nbuck; k += BINT)
        lcur[k] = bstart[k] + hist[b * nbuck + k];
    __syncthreads();
    const int start = b * chunk;
    const int end = min(E, start + chunk);
    int i = start + t;
    for (; i + BINT < end; i += 2 * BINT) {
        int s0 = clampi(src[i], n);
        int d0 = clampi(dst[i], n);
        int s1 = clampi(src[i + BINT], n);
        int d1 = clampi(dst[i + BINT], n);
        int p0 = atomicAdd(&lcur[d0 >> 8], 1);
        int p1 = atomicAdd(&lcur[d1 >> 8], 1);
        bbuf[p0] = ((d0 & 255) << 18) | s0;
        bbuf[p1] = ((d1 & 255) << 18) | s1;
    }
    if (i < end) {
        int s0 = clampi(src[i], n);
        int d0 = clampi(dst[i], n);
        int p0 = atomicAdd(&lcur[d0 >> 8], 1);
        bbuf[p0] = ((d0 & 255) << 18) | s0;
    }
}

// --- per-bucket: LDS hist -> scan -> rp/dinv -> clustered scatter --------
__global__ void k_bucket(const int* __restrict__ bbuf,
                         const int* __restrict__ bstart, int n,
                         int* __restrict__ rp, float* __restrict__ dinv,
                         int* __restrict__ adj) {
    __shared__ int lcnt[256];
    __shared__ int lsum[256];
    const int b = blockIdx.x;
    const int t = threadIdx.x;
    const int start = bstart[b];
    const int end = bstart[b + 1];

    lcnt[t] = 0;
    __syncthreads();
    for (int i = start + t; i < end; i += 256)
        atomicAdd(&lcnt[((unsigned)bbuf[i]) >> 18], 1);
    __syncthreads();

    int c = lcnt[t];
    lsum[t] = c;
    __syncthreads();
#pragma unroll
    for (int off = 1; off < 256; off <<= 1) {
        int v = (t >= off) ? lsum[t - off] : 0;
        __syncthreads();
        lsum[t] += v;
        __syncthreads();
    }
    int v = (b << 8) + t;
    if (v < n) {
        rp[v] = start + lsum[t];  // inclusive row end
        dinv[v] = rsqrtf((float)(c + 1));
    }
    int cur0 = start + lsum[t] - c;
    __syncthreads();
    lcnt[t] = cur0;  // reuse as write cursor
    __syncthreads();

    for (int i = start + t; i < end; i += 256) {
        int p = bbuf[i];
        int dl = ((unsigned)p) >> 18;
        int s = p & 0x3FFFF;
        int pos = atomicAdd(&lcnt[dl], 1);
        adj[pos] = s;
    }
}

// --- h1 = x @ W1, thread-per-(node,channel), fp16 output -----------------
__global__ void k_mm1(const float* __restrict__ x, const float* __restrict__ W,
                      int n, __half* __restrict__ h) {
    __shared__ float Ws[128 * 16];
    for (int i = threadIdx.x; i < 128 * 16; i += blockDim.x) Ws[i] = W[i];
    __syncthreads();
    long long total = (long long)n * 16;
    long long i = (long long)blockIdx.x * blockDim.x + threadIdx.x;
    long long stride = (long long)gridDim.x * blockDim.x;
    for (; i < total; i += stride) {
        int v = (int)(i >> 4);
        int c = (int)(i & 15);
        const float4* xr = (const float4*)(x + (size_t)v * 128);
        float acc = 0.f;
#pragma unroll
        for (int q = 0; q < 32; ++q) {
            float4 xv = xr[q];
            acc += xv.x * Ws[(4 * q + 0) * 16 + c] +
                   xv.y * Ws[(4 * q + 1) * 16 + c] +
                   xv.z * Ws[(4 * q + 2) * 16 + c] +
                   xv.w * Ws[(4 * q + 3) * 16 + c];
        }
        h[i] = __float2half(acc);
    }
}

// --- CSR gather + finalize, C=16, fp16 table -----------------------------
// HALF_OUT: store result as fp16 (z1 table) else f32 (pre).
template <bool RELU, bool BIAS, bool HALF_OUT>
__global__ void k_gather16(const int* __restrict__ rp,
                           const int* __restrict__ adj,
                           const float* __restrict__ dinv,
                           const __half* __restrict__ h,
                           const float* __restrict__ bias,
                           void* __restrict__ o, int n) {
    long long total = (long long)n * 16;
    long long i = (long long)blockIdx.x * blockDim.x + threadIdx.x;
    long long stride = (long long)gridDim.x * blockDim.x;
    for (; i < total; i += stride) {
        int v = (int)(i >> 4);
        int j = (int)(i & 15);
        int start = (v == 0) ? 0 : rp[v - 1];
        int end = rp[v];
        float acc0 = 0.f, acc1 = 0.f;
        int k = start;
        for (; k + 1 < end; k += 2) {
            int s0 = adj[k], s1 = adj[k + 1];
            acc0 += dinv[s0] * __half2float(h[(size_t)s0 * 16 + j]);
            acc1 += dinv[s1] * __half2float(h[(size_t)s1 * 16 + j]);
        }
        if (k < end) {
            int s0 = adj[k];
            acc0 += dinv[s0] * __half2float(h[(size_t)s0 * 16 + j]);
        }
        float dv = dinv[v];
        float val = dv * (acc0 + acc1) + dv * dv * __half2float(h[i]);
        if (BIAS) val += bias[j];
        if (RELU) val = fmaxf(val, 0.f);
        if (HALF_OUT)
            ((__half*)o)[i] = __float2half(val);
        else
            ((float*)o)[i] = val;
    }
}

// --- out = pre @ W2 + b2   (pre: n x 16 f32, W2: 16 x 32) ----------------
__global__ void k_out(const float* __restrict__ pre,
                      const float* __restrict__ W2,
                      const float* __restrict__ b2, float* __restrict__ out,
                      int n) {
    __shared__ float Ws[16 * 32];
    for (int i = threadIdx.x; i < 16 * 32; i += blockDim.x) Ws[i] = W2[i];
    __syncthreads();
    long long total = (long long)n * 32;
    long long i = (long long)blockIdx.x * blockDim.x + threadIdx.x;
    long long stride = (long long)gridDim.x * blockDim.x;
    for (; i < total; i += stride) {
        int v = (int)(i >> 5);
        int c = (int)(i & 31);
        const float* pr = pre + (size_t)v * 16;
        float acc = b2[c];
#pragma unroll
        for (int j = 0; j < 16; ++j) acc += pr[j] * Ws[j * 32 + c];
        out[i] = acc;
    }
}

static inline int blocks_for(long long total) {
    return (int)((total + TPB - 1) / TPB);
}

extern "C" void kernel_launch(void* const* d_in, const int* in_sizes, int n_in,
                              void* d_out, int out_size, void* d_ws,
                              size_t ws_size, hipStream_t stream) {
    const float* x = (const float*)d_in[0];
    const int* ei = (const int*)d_in[1];
    const float* W1 = (const float*)d_in[2];
    const float* b1 = (const float*)d_in[3];
    const float* W2 = (const float*)d_in[4];
    const float* b2 = (const float*)d_in[5];
    float* out = (float*)d_out;

    const int n = in_sizes[0] / 128;  // 200000 nodes
    const int E = in_sizes[1] / 2;    // 6400000 edges
    const int* src = ei;
    const int* dst = ei + E;
    const int nbuck = (n + 255) / 256;       // 782 (<= 1024 required)
    const int chunk = (E + NBB - 1) / NBB;   // 12500 edges per bin block

    // workspace layout:
    //  dinv: n f32 | rp: n i32 | adj: E i32 |
    //  region R (E i32 = 25.6 MB): bbuf during build, then
    //    h1h: n*16 half (6.4) | z1h: n*16 half (6.4) | pre: n*16 f32 (12.8)
    //  hist: NBB*nbuck i32 | colsum: nbuck | bstart: nbuck+1
    char* ws = (char*)d_ws;
    float* dinv = (float*)ws;
    int* rp = (int*)(ws + (size_t)n * 4);
    int* adj = (int*)(ws + (size_t)n * 8);
    char* R = ws + (size_t)n * 8 + (size_t)E * 4;
    __half* h1h = (__half*)R;
    __half* z1h = (__half*)(R + (size_t)n * 32);
    float* pre = (float*)(R + (size_t)n * 64);
    int* hist = (int*)(R + (size_t)E * 4);
    int* colsum = hist + (size_t)NBB * nbuck;
    int* bstart = colsum + nbuck;
    int* bbuf = (int*)R;  // E ints, dead before k_mm1 runs

    // --- CSR build (no global atomics) ---
    k_hist<<<NBB, BINT, 0, stream>>>(dst, E, n, nbuck, chunk, hist);
    k_scanA<<<(nbuck + 255) / 256, 256, 0, stream>>>(hist, nbuck, NBB, colsum);
    k_scanB<<<1, 256, 0, stream>>>(colsum, nbuck, E, bstart);
    k_bin<<<NBB, BINT, 0, stream>>>(src, dst, E, n, nbuck, chunk, hist, bstart,
                                    bbuf);
    k_bucket<<<nbuck, 256, 0, stream>>>(bbuf, bstart, n, rp, dinv, adj);

    // --- layer 1: h1 = x@W1 (fp16) ; z1 = relu(agg(h1)+b1) (fp16) ---
    k_mm1<<<blocks_for((long long)n * 16), TPB, 0, stream>>>(x, W1, n, h1h);
    k_gather16<true, true, true>
        <<<blocks_for((long long)n * 16), TPB, 0, stream>>>(rp, adj, dinv, h1h,
                                                            b1, z1h, n);

    // --- layer 2: pre = agg(z1) (f32) ; out = pre@W2 + b2 ---
    k_gather16<false, false, false>
        <<<blocks_for((long long)n * 16), TPB, 0, stream>>>(rp, adj, dinv, z1h,
                                                            nullptr, pre, n);
    k_out<<<blocks_for((long long)n * 32), TPB, 0, stream>>>(pre, W2, b2, out,
                                                             n);
}

// Round 10
// 475.913 us; speedup vs baseline: 1.1250x; 1.1250x over previous
//
#include <hip/hip_runtime.h>
#include <hip/hip_fp16.h>

// ---------------------------------------------------------------------------
// 2-layer GCN via device-built CSR + L2-resident scaled gather tables.
// CSR build (deterministic two-level counting sort, no global atomics):
//   k_hist -> k_scanA1/A2 (segmented) -> k_scanB -> k_scanA3 -> k_bin ->
//   k_bucket (rp/dinv/adj)
// Layers (aggregate-first on layer 2; aggregation is linear):
//   h1s = dinv * (x@W1)            fp16, split into lo/hi 8-ch tables (3.2 MB
//                                  each -> fits 4 MB per-XCD L2!)
//   z1s = dinv * relu(dinv*(agg(h1s)+h1s_self) + b1)     fp16 lo/hi
//   pre = dinv * (agg(z1s)+z1s_self)                     f32 lo/hi
//   out = pre @ W2 + b2
// Folding dinv into the table makes the gather ONE random 16 B load per
// edge: out[d] = dinv[d]*(sum_e hs[src] + hs[d]).  4-deep unroll for MLP.
// Bucket = 256 dst nodes; packing needs n < 2^18 (200000 ok).
// Region R (E*4 B = 25.6 MB) = bbuf during build, then exactly
// {h1sL,h1sH,z1sL,z1sH (4x3.2) + preL,preH (2x6.4)}.
// ---------------------------------------------------------------------------

#define TPB 256
#define BINT 256
#define SEGROWS 32

__device__ __forceinline__ int clampi(int v, int n) {
    return v < 0 ? 0 : (v >= n ? n - 1 : v);
}

// --- per-block LDS histogram over contiguous edge range ------------------
__global__ __launch_bounds__(BINT) void k_hist(const int* __restrict__ dst,
                                               int E, int n, int nbuck,
                                               int chunk,
                                               int* __restrict__ hist) {
    __shared__ int lh[1024];
    const int b = blockIdx.x;
    const int t = threadIdx.x;
    for (int k = t; k < 1024; k += BINT) lh[k] = 0;
    __syncthreads();
    const int start = b * chunk;
    const int end = min(E, start + chunk);
    for (int i = start + t; i < end; i += BINT)
        atomicAdd(&lh[clampi(dst[i], n) >> 8], 1);
    __syncthreads();
    for (int k = t; k < nbuck; k += BINT) hist[b * nbuck + k] = lh[k];
}

// --- segmented column scan stage 1: per-segment column sums --------------
__global__ void k_scanA1(const int* __restrict__ hist, int nbuck,
                         int* __restrict__ segsum) {
    int k = blockIdx.x * blockDim.x + threadIdx.x;
    int seg = blockIdx.y;
    if (k >= nbuck) return;
    const int* row = hist + (size_t)seg * SEGROWS * nbuck + k;
    int sum = 0;
#pragma unroll
    for (int b = 0; b < SEGROWS; ++b) sum += row[(size_t)b * nbuck];
    segsum[seg * nbuck + k] = sum;
}

// --- stage 2: serial scan over segments (nseg <= 32) + colsum ------------
__global__ void k_scanA2(int* __restrict__ segsum, int nbuck, int nseg,
                         int* __restrict__ colsum) {
    int k = blockIdx.x * blockDim.x + threadIdx.x;
    if (k >= nbuck) return;
    int run = 0;
    for (int sg = 0; sg < nseg; ++sg) {
        int v = segsum[sg * nbuck + k];
        segsum[sg * nbuck + k] = run;
        run += v;
    }
    colsum[k] = run;
}

// --- exclusive scan of colsum -> bstart[0..nbuck] ------------------------
__global__ void k_scanB(const int* __restrict__ colsum, int nbuck, int E,
                        int* __restrict__ bstart) {
    __shared__ int s[256];
    const int t = threadIdx.x;
    int loc[4];
    int a = 0;
#pragma unroll
    for (int i = 0; i < 4; ++i) {
        int idx = 4 * t + i;
        loc[i] = (idx < nbuck) ? colsum[idx] : 0;
        a += loc[i];
    }
    s[t] = a;
    __syncthreads();
#pragma unroll
    for (int off = 1; off < 256; off <<= 1) {
        int v = (t >= off) ? s[t - off] : 0;
        __syncthreads();
        s[t] += v;
        __syncthreads();
    }
    int base = s[t] - a;
#pragma unroll
    for (int i = 0; i < 4; ++i) {
        int idx = 4 * t + i;
        if (idx < nbuck) bstart[idx] = base;
        base += loc[i];
    }
    if (t == 255) bstart[nbuck] = E;
}

// --- stage 3: rewrite hist rows to global exclusive prefix ---------------
__global__ void k_scanA3(int* __restrict__ hist, int nbuck,
                         const int* __restrict__ segsum) {
    int k = blockIdx.x * blockDim.x + threadIdx.x;
    int seg = blockIdx.y;
    if (k >= nbuck) return;
    int run = segsum[seg * nbuck + k];
    int* row = hist + (size_t)seg * SEGROWS * nbuck + k;
#pragma unroll
    for (int b = 0; b < SEGROWS; ++b) {
        int v = row[(size_t)b * nbuck];
        row[(size_t)b * nbuck] = run;
        run += v;
    }
}

// --- binning: LDS cursors, LDS atomics only ------------------------------
__global__ __launch_bounds__(BINT) void k_bin(const int* __restrict__ src,
                                              const int* __restrict__ dst,
                                              int E, int n, int nbuck,
                                              int chunk,
                                              const int* __restrict__ hist,
                                              const int* __restrict__ bstart,
                                              int* __restrict__ bbuf) {
    __shared__ int lcur[1024];
    const int b = blockIdx.x;
    const int t = threadIdx.x;
    for (int k = t; k < nbuck; k += BINT)
        lcur[k] = bstart[k] + hist[b * nbuck + k];
    __syncthreads();
    const int start = b * chunk;
    const int end = min(E, start + chunk);
    int i = start + t;
    for (; i + BINT < end; i += 2 * BINT) {
        int s0 = clampi(src[i], n);
        int d0 = clampi(dst[i], n);
        int s1 = clampi(src[i + BINT], n);
        int d1 = clampi(dst[i + BINT], n);
        int p0 = atomicAdd(&lcur[d0 >> 8], 1);
        int p1 = atomicAdd(&lcur[d1 >> 8], 1);
        bbuf[p0] = ((d0 & 255) << 18) | s0;
        bbuf[p1] = ((d1 & 255) << 18) | s1;
    }
    if (i < end) {
        int s0 = clampi(src[i], n);
        int d0 = clampi(dst[i], n);
        int p0 = atomicAdd(&lcur[d0 >> 8], 1);
        bbuf[p0] = ((d0 & 255) << 18) | s0;
    }
}

// --- per-bucket: LDS hist -> scan -> rp/dinv -> clustered scatter --------
__global__ void k_bucket(const int* __restrict__ bbuf,
                         const int* __restrict__ bstart, int n,
                         int* __restrict__ rp, float* __restrict__ dinv,
                         int* __restrict__ adj) {
    __shared__ int lcnt[256];
    __shared__ int lsum[256];
    const int b = blockIdx.x;
    const int t = threadIdx.x;
    const int start = bstart[b];
    const int end = bstart[b + 1];

    lcnt[t] = 0;
    __syncthreads();
    for (int i = start + t; i < end; i += 256)
        atomicAdd(&lcnt[((unsigned)bbuf[i]) >> 18], 1);
    __syncthreads();

    int c = lcnt[t];
    lsum[t] = c;
    __syncthreads();
#pragma unroll
    for (int off = 1; off < 256; off <<= 1) {
        int v = (t >= off) ? lsum[t - off] : 0;
        __syncthreads();
        lsum[t] += v;
        __syncthreads();
    }
    int v = (b << 8) + t;
    if (v < n) {
        rp[v] = start + lsum[t];  // inclusive row end
        dinv[v] = rsqrtf((float)(c + 1));
    }
    int cur0 = start + lsum[t] - c;
    __syncthreads();
    lcnt[t] = cur0;  // reuse as write cursor
    __syncthreads();

    for (int i = start + t; i < end; i += 256) {
        int p = bbuf[i];
        int dl = ((unsigned)p) >> 18;
        int s = p & 0x3FFFF;
        int pos = atomicAdd(&lcnt[dl], 1);
        adj[pos] = s;
    }
}

// --- h1s = dinv * (x @ W1), fp16, split lo/hi 8-channel tables -----------
__global__ void k_mm1(const float* __restrict__ x, const float* __restrict__ W,
                      const float* __restrict__ dinv, int n,
                      __half* __restrict__ hlo, __half* __restrict__ hhi) {
    __shared__ float Ws[128 * 16];
    for (int i = threadIdx.x; i < 128 * 16; i += blockDim.x) Ws[i] = W[i];
    __syncthreads();
    long long total = (long long)n * 16;
    long long i = (long long)blockIdx.x * blockDim.x + threadIdx.x;
    long long stride = (long long)gridDim.x * blockDim.x;
    for (; i < total; i += stride) {
        int v = (int)(i >> 4);
        int c = (int)(i & 15);
        const float4* xr = (const float4*)(x + (size_t)v * 128);
        float acc = 0.f;
#pragma unroll
        for (int q = 0; q < 32; ++q) {
            float4 xv = xr[q];
            acc += xv.x * Ws[(4 * q + 0) * 16 + c] +
                   xv.y * Ws[(4 * q + 1) * 16 + c] +
                   xv.z * Ws[(4 * q + 2) * 16 + c] +
                   xv.w * Ws[(4 * q + 3) * 16 + c];
        }
        __half hv = __float2half(dinv[v] * acc);
        if (c < 8)
            hlo[(size_t)v * 8 + c] = hv;
        else
            hhi[(size_t)v * 8 + (c - 8)] = hv;
    }
}

// --- CSR gather over a scaled 8-channel fp16 table -----------------------
// val = dinv[v] * (sum_row hs[adj] + hs[v]); L1: relu(+bias)->scaled fp16,
// else raw f32. One random 16 B load per edge; 4 independent accumulators.
template <bool L1>
__global__ void k_gather8(const int* __restrict__ rp,
                          const int* __restrict__ adj,
                          const float* __restrict__ dinv,
                          const __half* __restrict__ hs,
                          const float* __restrict__ bias, int ch0,
                          void* __restrict__ o, int n) {
    long long total = (long long)n * 8;
    long long i = (long long)blockIdx.x * blockDim.x + threadIdx.x;
    long long stride = (long long)gridDim.x * blockDim.x;
    for (; i < total; i += stride) {
        int v = (int)(i >> 3);
        int j = (int)(i & 7);
        int start = (v == 0) ? 0 : rp[v - 1];
        int end = rp[v];
        float a0 = 0.f, a1 = 0.f, a2 = 0.f, a3 = 0.f;
        int k = start;
        for (; k + 3 < end; k += 4) {
            int s0 = adj[k], s1 = adj[k + 1], s2 = adj[k + 2], s3 = adj[k + 3];
            a0 += __half2float(hs[(size_t)s0 * 8 + j]);
            a1 += __half2float(hs[(size_t)s1 * 8 + j]);
            a2 += __half2float(hs[(size_t)s2 * 8 + j]);
            a3 += __half2float(hs[(size_t)s3 * 8 + j]);
        }
        for (; k < end; ++k) a0 += __half2float(hs[(size_t)adj[k] * 8 + j]);
        float dv = dinv[v];
        float val = dv * (((a0 + a1) + (a2 + a3)) + __half2float(hs[i]));
        if (L1) {
            val = fmaxf(val + bias[ch0 + j], 0.f);
            ((__half*)o)[i] = __float2half(dv * val);
        } else {
            ((float*)o)[i] = val;
        }
    }
}

// --- out = [preL|preH] @ W2 + b2 -----------------------------------------
__global__ void k_out(const float* __restrict__ preL,
                      const float* __restrict__ preH,
                      const float* __restrict__ W2,
                      const float* __restrict__ b2, float* __restrict__ out,
                      int n) {
    __shared__ float Ws[16 * 32];
    for (int i = threadIdx.x; i < 16 * 32; i += blockDim.x) Ws[i] = W2[i];
    __syncthreads();
    long long total = (long long)n * 32;
    long long i = (long long)blockIdx.x * blockDim.x + threadIdx.x;
    long long stride = (long long)gridDim.x * blockDim.x;
    for (; i < total; i += stride) {
        int v = (int)(i >> 5);
        int c = (int)(i & 31);
        const float* pl = preL + (size_t)v * 8;
        const float* ph = preH + (size_t)v * 8;
        float acc = b2[c];
#pragma unroll
        for (int j = 0; j < 8; ++j) acc += pl[j] * Ws[j * 32 + c];
#pragma unroll
        for (int j = 0; j < 8; ++j) acc += ph[j] * Ws[(8 + j) * 32 + c];
        out[i] = acc;
    }
}

static inline int blocks_for(long long total) {
    return (int)((total + TPB - 1) / TPB);
}

extern "C" void kernel_launch(void* const* d_in, const int* in_sizes, int n_in,
                              void* d_out, int out_size, void* d_ws,
                              size_t ws_size, hipStream_t stream) {
    const float* x = (const float*)d_in[0];
    const int* ei = (const int*)d_in[1];
    const float* W1 = (const float*)d_in[2];
    const float* b1 = (const float*)d_in[3];
    const float* W2 = (const float*)d_in[4];
    const float* b2 = (const float*)d_in[5];
    float* out = (float*)d_out;

    const int n = in_sizes[0] / 128;  // 200000 nodes
    const int E = in_sizes[1] / 2;    // 6400000 edges
    const int* src = ei;
    const int* dst = ei + E;
    const int nbuck = (n + 255) / 256;  // 782 (<= 1024 required)

    // base workspace: dinv n f32 | rp n i32 | adj E i32 | R = E i32 (25.6 MB)
    char* ws = (char*)d_ws;
    float* dinv = (float*)ws;
    int* rp = (int*)(ws + (size_t)n * 4);
    int* adj = (int*)(ws + (size_t)n * 8);
    char* R = ws + (size_t)n * 8 + (size_t)E * 4;
    size_t base_bytes = (size_t)n * 8 + (size_t)E * 8;

    // choose NBB by available scratch (hist = NBB*nbuck*4 after R)
    size_t need1024 = base_bytes + ((size_t)1024 + 33) * nbuck * 4 + 8192;
    const int NBB = (ws_size >= need1024) ? 1024 : 512;
    const int nseg = NBB / SEGROWS;
    const int chunk = (E + NBB - 1) / NBB;

    int* hist = (int*)(R + (size_t)E * 4);
    int* segsum = hist + (size_t)NBB * nbuck;
    int* colsum = segsum + (size_t)nseg * nbuck;
    int* bstart = colsum + nbuck;
    int* bbuf = (int*)R;  // E ints, dead before k_mm1 runs

    // region R after build: h1sL/h1sH/z1sL/z1sH (n*8 half) + preL/preH (n*8 f32)
    __half* h1sL = (__half*)R;
    __half* h1sH = (__half*)(R + (size_t)n * 16);
    __half* z1sL = (__half*)(R + (size_t)n * 32);
    __half* z1sH = (__half*)(R + (size_t)n * 48);
    float* preL = (float*)(R + (size_t)n * 64);
    float* preH = (float*)(R + (size_t)n * 96);

    const int cb = (nbuck + 255) / 256;  // 4

    // --- CSR build (no global atomics) ---
    k_hist<<<NBB, BINT, 0, stream>>>(dst, E, n, nbuck, chunk, hist);
    k_scanA1<<<dim3(cb, nseg), 256, 0, stream>>>(hist, nbuck, segsum);
    k_scanA2<<<cb, 256, 0, stream>>>(segsum, nbuck, nseg, colsum);
    k_scanB<<<1, 256, 0, stream>>>(colsum, nbuck, E, bstart);
    k_scanA3<<<dim3(cb, nseg), 256, 0, stream>>>(hist, nbuck, segsum);
    k_bin<<<NBB, BINT, 0, stream>>>(src, dst, E, n, nbuck, chunk, hist, bstart,
                                    bbuf);
    k_bucket<<<nbuck, 256, 0, stream>>>(bbuf, bstart, n, rp, dinv, adj);

    // --- layer 1 ---
    k_mm1<<<blocks_for((long long)n * 16), TPB, 0, stream>>>(x, W1, dinv, n,
                                                             h1sL, h1sH);
    k_gather8<true><<<blocks_for((long long)n * 8), TPB, 0, stream>>>(
        rp, adj, dinv, h1sL, b1, 0, z1sL, n);
    k_gather8<true><<<blocks_for((long long)n * 8), TPB, 0, stream>>>(
        rp, adj, dinv, h1sH, b1, 8, z1sH, n);

    // --- layer 2 ---
    k_gather8<false><<<blocks_for((long long)n * 8), TPB, 0, stream>>>(
        rp, adj, dinv, z1sL, nullptr, 0, preL, n);
    k_gather8<false><<<blocks_for((long long)n * 8), TPB, 0, stream>>>(
        rp, adj, dinv, z1sH, nullptr, 8, preH, n);
    k_out<<<blocks_for((long long)n * 32), TPB, 0, stream>>>(preL, preH, W2, b2,
                                                             out, n);
}

// Round 11
// 431.109 us; speedup vs baseline: 1.2420x; 1.1039x over previous
//
#include <hip/hip_runtime.h>
#include <hip/hip_fp16.h>

// ---------------------------------------------------------------------------
// 2-layer GCN via device-built CSR + L2-resident scaled gather tables.
// CSR build (deterministic two-level counting sort, no global atomics):
//   k_hist -> k_scanA1/A2 (segmented) -> k_scanB -> k_scanA3 -> k_bin ->
//   k_bucket (rp/dinv/adj)
// Bucket = 1024 dst nodes (nbuck=196): k_bin's active write window is
// 196 cachelines (12.5 KB) per block -> lines fill before eviction (round-10
// showed 159 MB HBM writes for a 25.6 MB buffer with 1024-entry windows).
// Packing (d&1023)<<18 | s needs n < 2^18 (200000 ok).
// Layers (aggregate-first on layer 2; aggregation is linear):
//   h1s = dinv * (x@W1)          fp16 lo/hi 8-ch tables (3.2 MB -> L2-fit)
//   z1s = dinv * relu(agg+b1)    fp16 lo/hi
//   pre = agg(z1s)               f32 lo/hi
//   out = pre @ W2 + b2
// Gather: ONE random 16 B load per edge (dinv folded into table), 4-deep MLP.
// Region R (E*4 B) = bbuf during build, then {h1s,z1s,pre} exactly.
// ---------------------------------------------------------------------------

#define TPB 256
#define BINT 256
#define SEGROWS 32
#define BUCKSH 10                 // log2(nodes per bucket)
#define BUCKN (1 << BUCKSH)       // 1024 nodes per bucket

__device__ __forceinline__ int clampi(int v, int n) {
    return v < 0 ? 0 : (v >= n ? n - 1 : v);
}

// --- per-block LDS histogram over contiguous edge range ------------------
__global__ __launch_bounds__(BINT) void k_hist(const int* __restrict__ dst,
                                               int E, int n, int nbuck,
                                               int chunk,
                                               int* __restrict__ hist) {
    __shared__ int lh[256];
    const int b = blockIdx.x;
    const int t = threadIdx.x;
    lh[t] = 0;
    __syncthreads();
    const int start = b * chunk;
    const int end = min(E, start + chunk);
    for (int i = start + t; i < end; i += BINT)
        atomicAdd(&lh[clampi(dst[i], n) >> BUCKSH], 1);
    __syncthreads();
    for (int k = t; k < nbuck; k += BINT) hist[b * nbuck + k] = lh[k];
}

// --- segmented column scan stage 1: per-segment column sums --------------
__global__ void k_scanA1(const int* __restrict__ hist, int nbuck,
                         int* __restrict__ segsum) {
    int k = blockIdx.x * blockDim.x + threadIdx.x;
    int seg = blockIdx.y;
    if (k >= nbuck) return;
    const int* row = hist + (size_t)seg * SEGROWS * nbuck + k;
    int sum = 0;
#pragma unroll
    for (int b = 0; b < SEGROWS; ++b) sum += row[(size_t)b * nbuck];
    segsum[seg * nbuck + k] = sum;
}

// --- stage 2: serial scan over segments (nseg <= 32) + colsum ------------
__global__ void k_scanA2(int* __restrict__ segsum, int nbuck, int nseg,
                         int* __restrict__ colsum) {
    int k = blockIdx.x * blockDim.x + threadIdx.x;
    if (k >= nbuck) return;
    int run = 0;
    for (int sg = 0; sg < nseg; ++sg) {
        int v = segsum[sg * nbuck + k];
        segsum[sg * nbuck + k] = run;
        run += v;
    }
    colsum[k] = run;
}

// --- exclusive scan of colsum -> bstart[0..nbuck] ------------------------
__global__ void k_scanB(const int* __restrict__ colsum, int nbuck, int E,
                        int* __restrict__ bstart) {
    __shared__ int s[256];
    const int t = threadIdx.x;
    int loc[4];
    int a = 0;
#pragma unroll
    for (int i = 0; i < 4; ++i) {
        int idx = 4 * t + i;
        loc[i] = (idx < nbuck) ? colsum[idx] : 0;
        a += loc[i];
    }
    s[t] = a;
    __syncthreads();
#pragma unroll
    for (int off = 1; off < 256; off <<= 1) {
        int v = (t >= off) ? s[t - off] : 0;
        __syncthreads();
        s[t] += v;
        __syncthreads();
    }
    int base = s[t] - a;
#pragma unroll
    for (int i = 0; i < 4; ++i) {
        int idx = 4 * t + i;
        if (idx < nbuck) bstart[idx] = base;
        base += loc[i];
    }
    if (t == 255) bstart[nbuck] = E;
}

// --- stage 3: rewrite hist rows to global exclusive prefix ---------------
__global__ void k_scanA3(int* __restrict__ hist, int nbuck,
                         const int* __restrict__ segsum) {
    int k = blockIdx.x * blockDim.x + threadIdx.x;
    int seg = blockIdx.y;
    if (k >= nbuck) return;
    int run = segsum[seg * nbuck + k];
    int* row = hist + (size_t)seg * SEGROWS * nbuck + k;
#pragma unroll
    for (int b = 0; b < SEGROWS; ++b) {
        int v = row[(size_t)b * nbuck];
        row[(size_t)b * nbuck] = run;
        run += v;
    }
}

// --- binning: LDS cursors, LDS atomics only ------------------------------
__global__ __launch_bounds__(BINT) void k_bin(const int* __restrict__ src,
                                              const int* __restrict__ dst,
                                              int E, int n, int nbuck,
                                              int chunk,
                                              const int* __restrict__ hist,
                                              const int* __restrict__ bstart,
                                              int* __restrict__ bbuf) {
    __shared__ int lcur[256];
    const int b = blockIdx.x;
    const int t = threadIdx.x;
    for (int k = t; k < nbuck; k += BINT)
        lcur[k] = bstart[k] + hist[b * nbuck + k];
    __syncthreads();
    const int start = b * chunk;
    const int end = min(E, start + chunk);
    int i = start + t;
    for (; i + BINT < end; i += 2 * BINT) {
        int s0 = clampi(src[i], n);
        int d0 = clampi(dst[i], n);
        int s1 = clampi(src[i + BINT], n);
        int d1 = clampi(dst[i + BINT], n);
        int p0 = atomicAdd(&lcur[d0 >> BUCKSH], 1);
        int p1 = atomicAdd(&lcur[d1 >> BUCKSH], 1);
        bbuf[p0] = ((d0 & (BUCKN - 1)) << 18) | s0;
        bbuf[p1] = ((d1 & (BUCKN - 1)) << 18) | s1;
    }
    if (i < end) {
        int s0 = clampi(src[i], n);
        int d0 = clampi(dst[i], n);
        int p0 = atomicAdd(&lcur[d0 >> BUCKSH], 1);
        bbuf[p0] = ((d0 & (BUCKN - 1)) << 18) | s0;
    }
}

// --- per-bucket (1024 nodes, 1024 thr): hist -> scan -> rp/dinv -> adj ---
__global__ __launch_bounds__(1024) void k_bucket(const int* __restrict__ bbuf,
                                                 const int* __restrict__ bstart,
                                                 int n, int* __restrict__ rp,
                                                 float* __restrict__ dinv,
                                                 int* __restrict__ adj) {
    __shared__ int lcnt[1024];
    __shared__ int ls[1024];
    const int b = blockIdx.x;
    const int t = threadIdx.x;
    const int start = bstart[b];
    const int end = bstart[b + 1];

    lcnt[t] = 0;
    __syncthreads();
    for (int i = start + t; i < end; i += 1024)
        atomicAdd(&lcnt[((unsigned)bbuf[i]) >> 18], 1);
    __syncthreads();

    int c = lcnt[t];
    ls[t] = c;
    __syncthreads();
#pragma unroll
    for (int off = 1; off < 1024; off <<= 1) {
        int v = (t >= off) ? ls[t - off] : 0;
        __syncthreads();
        ls[t] += v;
        __syncthreads();
    }
    int v = (b << BUCKSH) + t;
    if (v < n) {
        rp[v] = start + ls[t];  // inclusive row end
        dinv[v] = rsqrtf((float)(c + 1));
    }
    int cur0 = start + ls[t] - c;
    __syncthreads();
    lcnt[t] = cur0;  // reuse as write cursor
    __syncthreads();

    for (int i = start + t; i < end; i += 1024) {
        int p = bbuf[i];
        int dl = ((unsigned)p) >> 18;
        int s = p & 0x3FFFF;
        int pos = atomicAdd(&lcnt[dl], 1);
        adj[pos] = s;
    }
}

// --- h1s = dinv * (x @ W1), fp16, split lo/hi 8-channel tables -----------
__global__ void k_mm1(const float* __restrict__ x, const float* __restrict__ W,
                      const float* __restrict__ dinv, int n,
                      __half* __restrict__ hlo, __half* __restrict__ hhi) {
    __shared__ float Ws[128 * 16];
    for (int i = threadIdx.x; i < 128 * 16; i += blockDim.x) Ws[i] = W[i];
    __syncthreads();
    long long total = (long long)n * 16;
    long long i = (long long)blockIdx.x * blockDim.x + threadIdx.x;
    long long stride = (long long)gridDim.x * blockDim.x;
    for (; i < total; i += stride) {
        int v = (int)(i >> 4);
        int c = (int)(i & 15);
        const float4* xr = (const float4*)(x + (size_t)v * 128);
        float acc = 0.f;
#pragma unroll
        for (int q = 0; q < 32; ++q) {
            float4 xv = xr[q];
            acc += xv.x * Ws[(4 * q + 0) * 16 + c] +
                   xv.y * Ws[(4 * q + 1) * 16 + c] +
                   xv.z * Ws[(4 * q + 2) * 16 + c] +
                   xv.w * Ws[(4 * q + 3) * 16 + c];
        }
        __half hv = __float2half(dinv[v] * acc);
        if (c < 8)
            hlo[(size_t)v * 8 + c] = hv;
        else
            hhi[(size_t)v * 8 + (c - 8)] = hv;
    }
}

// --- CSR gather over a scaled 8-channel fp16 table -----------------------
template <bool L1>
__global__ void k_gather8(const int* __restrict__ rp,
                          const int* __restrict__ adj,
                          const float* __restrict__ dinv,
                          const __half* __restrict__ hs,
                          const float* __restrict__ bias, int ch0,
                          void* __restrict__ o, int n) {
    long long total = (long long)n * 8;
    long long i = (long long)blockIdx.x * blockDim.x + threadIdx.x;
    long long stride = (long long)gridDim.x * blockDim.x;
    for (; i < total; i += stride) {
        int v = (int)(i >> 3);
        int j = (int)(i & 7);
        int start = (v == 0) ? 0 : rp[v - 1];
        int end = rp[v];
        float a0 = 0.f, a1 = 0.f, a2 = 0.f, a3 = 0.f;
        int k = start;
        for (; k + 3 < end; k += 4) {
            int s0 = adj[k], s1 = adj[k + 1], s2 = adj[k + 2], s3 = adj[k + 3];
            a0 += __half2float(hs[(size_t)s0 * 8 + j]);
            a1 += __half2float(hs[(size_t)s1 * 8 + j]);
            a2 += __half2float(hs[(size_t)s2 * 8 + j]);
            a3 += __half2float(hs[(size_t)s3 * 8 + j]);
        }
        for (; k < end; ++k) a0 += __half2float(hs[(size_t)adj[k] * 8 + j]);
        float dv = dinv[v];
        float val = dv * (((a0 + a1) + (a2 + a3)) + __half2float(hs[i]));
        if (L1) {
            val = fmaxf(val + bias[ch0 + j], 0.f);
            ((__half*)o)[i] = __float2half(dv * val);
        } else {
            ((float*)o)[i] = val;
        }
    }
}

// --- out = [preL|preH] @ W2 + b2 -----------------------------------------
__global__ void k_out(const float* __restrict__ preL,
                      const float* __restrict__ preH,
                      const float* __restrict__ W2,
                      const float* __restrict__ b2, float* __restrict__ out,
                      int n) {
    __shared__ float Ws[16 * 32];
    for (int i = threadIdx.x; i < 16 * 32; i += blockDim.x) Ws[i] = W2[i];
    __syncthreads();
    long long total = (long long)n * 32;
    long long i = (long long)blockIdx.x * blockDim.x + threadIdx.x;
    long long stride = (long long)gridDim.x * blockDim.x;
    for (; i < total; i += stride) {
        int v = (int)(i >> 5);
        int c = (int)(i & 31);
        const float* pl = preL + (size_t)v * 8;
        const float* ph = preH + (size_t)v * 8;
        float acc = b2[c];
#pragma unroll
        for (int j = 0; j < 8; ++j) acc += pl[j] * Ws[j * 32 + c];
#pragma unroll
        for (int j = 0; j < 8; ++j) acc += ph[j] * Ws[(8 + j) * 32 + c];
        out[i] = acc;
    }
}

static inline int blocks_for(long long total) {
    return (int)((total + TPB - 1) / TPB);
}

extern "C" void kernel_launch(void* const* d_in, const int* in_sizes, int n_in,
                              void* d_out, int out_size, void* d_ws,
                              size_t ws_size, hipStream_t stream) {
    const float* x = (const float*)d_in[0];
    const int* ei = (const int*)d_in[1];
    const float* W1 = (const float*)d_in[2];
    const float* b1 = (const float*)d_in[3];
    const float* W2 = (const float*)d_in[4];
    const float* b2 = (const float*)d_in[5];
    float* out = (float*)d_out;

    const int n = in_sizes[0] / 128;  // 200000 nodes
    const int E = in_sizes[1] / 2;    // 6400000 edges
    const int* src = ei;
    const int* dst = ei + E;
    const int nbuck = (n + BUCKN - 1) / BUCKN;  // 196 (<= 256 required)

    // base workspace: dinv n f32 | rp n i32 | adj E i32 | R = E i32 (25.6 MB)
    char* ws = (char*)d_ws;
    float* dinv = (float*)ws;
    int* rp = (int*)(ws + (size_t)n * 4);
    int* adj = (int*)(ws + (size_t)n * 8);
    char* R = ws + (size_t)n * 8 + (size_t)E * 4;
    size_t base_bytes = (size_t)n * 8 + (size_t)E * 8;

    // choose NBB by available scratch (hist = NBB*nbuck*4 after R)
    size_t need1024 = base_bytes + ((size_t)1024 + 33) * nbuck * 4 + 8192;
    const int NBB = (ws_size >= need1024) ? 1024 : 512;
    const int nseg = NBB / SEGROWS;
    const int chunk = (E + NBB - 1) / NBB;

    int* hist = (int*)(R + (size_t)E * 4);
    int* segsum = hist + (size_t)NBB * nbuck;
    int* colsum = segsum + (size_t)nseg * nbuck;
    int* bstart = colsum + nbuck;
    int* bbuf = (int*)R;  // E ints, dead before k_mm1 runs

    // region R after build: h1sL/h1sH/z1sL/z1sH (n*8 half) + preL/preH (n*8 f32)
    __half* h1sL = (__half*)R;
    __half* h1sH = (__half*)(R + (size_t)n * 16);
    __half* z1sL = (__half*)(R + (size_t)n * 32);
    __half* z1sH = (__half*)(R + (size_t)n * 48);
    float* preL = (float*)(R + (size_t)n * 64);
    float* preH = (float*)(R + (size_t)n * 96);

    const int cb = (nbuck + 255) / 256;  // 1

    // --- CSR build (no global atomics) ---
    k_hist<<<NBB, BINT, 0, stream>>>(dst, E, n, nbuck, chunk, hist);
    k_scanA1<<<dim3(cb, nseg), 256, 0, stream>>>(hist, nbuck, segsum);
    k_scanA2<<<cb, 256, 0, stream>>>(segsum, nbuck, nseg, colsum);
    k_scanB<<<1, 256, 0, stream>>>(colsum, nbuck, E, bstart);
    k_scanA3<<<dim3(cb, nseg), 256, 0, stream>>>(hist, nbuck, segsum);
    k_bin<<<NBB, BINT, 0, stream>>>(src, dst, E, n, nbuck, chunk, hist, bstart,
                                    bbuf);
    k_bucket<<<nbuck, 1024, 0, stream>>>(bbuf, bstart, n, rp, dinv, adj);

    // --- layer 1 ---
    k_mm1<<<blocks_for((long long)n * 16), TPB, 0, stream>>>(x, W1, dinv, n,
                                                             h1sL, h1sH);
    k_gather8<true><<<blocks_for((long long)n * 8), TPB, 0, stream>>>(
        rp, adj, dinv, h1sL, b1, 0, z1sL, n);
    k_gather8<true><<<blocks_for((long long)n * 8), TPB, 0, stream>>>(
        rp, adj, dinv, h1sH, b1, 8, z1sH, n);

    // --- layer 2 ---
    k_gather8<false><<<blocks_for((long long)n * 8), TPB, 0, stream>>>(
        rp, adj, dinv, z1sL, nullptr, 0, preL, n);
    k_gather8<false><<<blocks_for((long long)n * 8), TPB, 0, stream>>>(
        rp, adj, dinv, z1sH, nullptr, 8, preH, n);
    k_out<<<blocks_for((long long)n * 32), TPB, 0, stream>>>(preL, preH, W2, b2,
                                                             out, n);
}

// Round 12
// 415.252 us; speedup vs baseline: 1.2894x; 1.0382x over previous
//
#include <hip/hip_runtime.h>
#include <hip/hip_fp16.h>

// ---------------------------------------------------------------------------
// 2-layer GCN via device-built CSR + L2-resident scaled gather tables.
// CSR build (deterministic two-level counting sort, no global atomics):
//   k_hist -> k_scanA1/A2 (segmented) -> k_scanB -> k_scanA3 -> k_bin ->
//   k_bucket (rp/dinv/adj).  Bucket = 1024 dst nodes (write-window fix).
// Layers (aggregate-first on layer 2; aggregation is linear):
//   h1s = dinv * (x@W1)          fp16 lo/hi 8-ch tables (3.2 MB -> L2-fit)
//   z1s = dinv * relu(agg+b1)    fp16 lo/hi
//   pre = agg(z1s)               f32 lo/hi
//   out = pre @ W2 + b2
// k_mm1 is LDS-staged: 512-thr block stages 32 x-rows (16 KB, coalesced)
// then computes 32x16 outputs from LDS. Round-11's broadcast-load version
// was issue-bound at 92 us (1.1 TB/s effective, VALUBusy 20%).
// Gather: ONE random 16 B load per edge (dinv folded into table), 4-deep MLP.
// Region R (E*4 B) = bbuf during build, then {h1s,z1s,pre} exactly.
// ---------------------------------------------------------------------------

#define TPB 256
#define BINT 256
#define SEGROWS 32
#define BUCKSH 10                 // log2(nodes per bucket)
#define BUCKN (1 << BUCKSH)       // 1024 nodes per bucket
#define MMN 32                    // nodes per mm1 tile

__device__ __forceinline__ int clampi(int v, int n) {
    return v < 0 ? 0 : (v >= n ? n - 1 : v);
}

// --- per-block LDS histogram over contiguous edge range ------------------
__global__ __launch_bounds__(BINT) void k_hist(const int* __restrict__ dst,
                                               int E, int n, int nbuck,
                                               int chunk,
                                               int* __restrict__ hist) {
    __shared__ int lh[256];
    const int b = blockIdx.x;
    const int t = threadIdx.x;
    lh[t] = 0;
    __syncthreads();
    const int start = b * chunk;
    const int end = min(E, start + chunk);
    for (int i = start + t; i < end; i += BINT)
        atomicAdd(&lh[clampi(dst[i], n) >> BUCKSH], 1);
    __syncthreads();
    for (int k = t; k < nbuck; k += BINT) hist[b * nbuck + k] = lh[k];
}

// --- segmented column scan stage 1: per-segment column sums --------------
__global__ void k_scanA1(const int* __restrict__ hist, int nbuck,
                         int* __restrict__ segsum) {
    int k = blockIdx.x * blockDim.x + threadIdx.x;
    int seg = blockIdx.y;
    if (k >= nbuck) return;
    const int* row = hist + (size_t)seg * SEGROWS * nbuck + k;
    int sum = 0;
#pragma unroll
    for (int b = 0; b < SEGROWS; ++b) sum += row[(size_t)b * nbuck];
    segsum[seg * nbuck + k] = sum;
}

// --- stage 2: serial scan over segments (nseg <= 32) + colsum ------------
__global__ void k_scanA2(int* __restrict__ segsum, int nbuck, int nseg,
                         int* __restrict__ colsum) {
    int k = blockIdx.x * blockDim.x + threadIdx.x;
    if (k >= nbuck) return;
    int run = 0;
    for (int sg = 0; sg < nseg; ++sg) {
        int v = segsum[sg * nbuck + k];
        segsum[sg * nbuck + k] = run;
        run += v;
    }
    colsum[k] = run;
}

// --- exclusive scan of colsum -> bstart[0..nbuck] ------------------------
__global__ void k_scanB(const int* __restrict__ colsum, int nbuck, int E,
                        int* __restrict__ bstart) {
    __shared__ int s[256];
    const int t = threadIdx.x;
    int loc[4];
    int a = 0;
#pragma unroll
    for (int i = 0; i < 4; ++i) {
        int idx = 4 * t + i;
        loc[i] = (idx < nbuck) ? colsum[idx] : 0;
        a += loc[i];
    }
    s[t] = a;
    __syncthreads();
#pragma unroll
    for (int off = 1; off < 256; off <<= 1) {
        int v = (t >= off) ? s[t - off] : 0;
        __syncthreads();
        s[t] += v;
        __syncthreads();
    }
    int base = s[t] - a;
#pragma unroll
    for (int i = 0; i < 4; ++i) {
        int idx = 4 * t + i;
        if (idx < nbuck) bstart[idx] = base;
        base += loc[i];
    }
    if (t == 255) bstart[nbuck] = E;
}

// --- stage 3: rewrite hist rows to global exclusive prefix ---------------
__global__ void k_scanA3(int* __restrict__ hist, int nbuck,
                         const int* __restrict__ segsum) {
    int k = blockIdx.x * blockDim.x + threadIdx.x;
    int seg = blockIdx.y;
    if (k >= nbuck) return;
    int run = segsum[seg * nbuck + k];
    int* row = hist + (size_t)seg * SEGROWS * nbuck + k;
#pragma unroll
    for (int b = 0; b < SEGROWS; ++b) {
        int v = row[(size_t)b * nbuck];
        row[(size_t)b * nbuck] = run;
        run += v;
    }
}

// --- binning: LDS cursors, LDS atomics only ------------------------------
__global__ __launch_bounds__(BINT) void k_bin(const int* __restrict__ src,
                                              const int* __restrict__ dst,
                                              int E, int n, int nbuck,
                                              int chunk,
                                              const int* __restrict__ hist,
                                              const int* __restrict__ bstart,
                                              int* __restrict__ bbuf) {
    __shared__ int lcur[256];
    const int b = blockIdx.x;
    const int t = threadIdx.x;
    for (int k = t; k < nbuck; k += BINT)
        lcur[k] = bstart[k] + hist[b * nbuck + k];
    __syncthreads();
    const int start = b * chunk;
    const int end = min(E, start + chunk);
    int i = start + t;
    for (; i + BINT < end; i += 2 * BINT) {
        int s0 = clampi(src[i], n);
        int d0 = clampi(dst[i], n);
        int s1 = clampi(src[i + BINT], n);
        int d1 = clampi(dst[i + BINT], n);
        int p0 = atomicAdd(&lcur[d0 >> BUCKSH], 1);
        int p1 = atomicAdd(&lcur[d1 >> BUCKSH], 1);
        bbuf[p0] = ((d0 & (BUCKN - 1)) << 18) | s0;
        bbuf[p1] = ((d1 & (BUCKN - 1)) << 18) | s1;
    }
    if (i < end) {
        int s0 = clampi(src[i], n);
        int d0 = clampi(dst[i], n);
        int p0 = atomicAdd(&lcur[d0 >> BUCKSH], 1);
        bbuf[p0] = ((d0 & (BUCKN - 1)) << 18) | s0;
    }
}

// --- per-bucket (1024 nodes, 1024 thr): hist -> scan -> rp/dinv -> adj ---
__global__ __launch_bounds__(1024) void k_bucket(const int* __restrict__ bbuf,
                                                 const int* __restrict__ bstart,
                                                 int n, int* __restrict__ rp,
                                                 float* __restrict__ dinv,
                                                 int* __restrict__ adj) {
    __shared__ int lcnt[1024];
    __shared__ int ls[1024];
    const int b = blockIdx.x;
    const int t = threadIdx.x;
    const int start = bstart[b];
    const int end = bstart[b + 1];

    lcnt[t] = 0;
    __syncthreads();
    for (int i = start + t; i < end; i += 1024)
        atomicAdd(&lcnt[((unsigned)bbuf[i]) >> 18], 1);
    __syncthreads();

    int c = lcnt[t];
    ls[t] = c;
    __syncthreads();
#pragma unroll
    for (int off = 1; off < 1024; off <<= 1) {
        int v = (t >= off) ? ls[t - off] : 0;
        __syncthreads();
        ls[t] += v;
        __syncthreads();
    }
    int v = (b << BUCKSH) + t;
    if (v < n) {
        rp[v] = start + ls[t];  // inclusive row end
        dinv[v] = rsqrtf((float)(c + 1));
    }
    int cur0 = start + ls[t] - c;
    __syncthreads();
    lcnt[t] = cur0;  // reuse as write cursor
    __syncthreads();

    for (int i = start + t; i < end; i += 1024) {
        int p = bbuf[i];
        int dl = ((unsigned)p) >> 18;
        int s = p & 0x3FFFF;
        int pos = atomicAdd(&lcnt[dl], 1);
        adj[pos] = s;
    }
}

// --- h1s = dinv*(x@W1): LDS-staged tile (32 nodes), 512 thr --------------
// load: 1024 float4 coalesced into xs (row pad 132 -> distinct banks for the
// 4 node-groups of a wave). compute: thread=(node,ch) reads xs as float4.
__global__ __launch_bounds__(512) void k_mm1(const float* __restrict__ x,
                                             const float* __restrict__ W,
                                             const float* __restrict__ dinv,
                                             int n, __half* __restrict__ hlo,
                                             __half* __restrict__ hhi) {
    __shared__ float Ws[128 * 16];
    __shared__ float xs[MMN * 132];
    const int t = threadIdx.x;
    for (int i = t; i < 128 * 16; i += 512) Ws[i] = W[i];
    const int node0 = blockIdx.x * MMN;
    {
        const float4* xg = (const float4*)(x + (size_t)node0 * 128);
#pragma unroll
        for (int it = 0; it < 2; ++it) {
            int idx = it * 512 + t;  // float4 index in tile, 0..1023
            int row = idx >> 5;
            int c4 = idx & 31;
            if (node0 + row < n) {
                float4 v = xg[(size_t)row * 32 + c4];
                float* dp = &xs[row * 132 + c4 * 4];
                dp[0] = v.x;
                dp[1] = v.y;
                dp[2] = v.z;
                dp[3] = v.w;
            }
        }
    }
    __syncthreads();
    const int node = node0 + (t >> 4);
    const int c = t & 15;
    if (node < n) {
        const float4* xr4 = (const float4*)&xs[(t >> 4) * 132];
        float acc = 0.f;
#pragma unroll
        for (int q = 0; q < 32; ++q) {
            float4 xv = xr4[q];
            acc += xv.x * Ws[(4 * q + 0) * 16 + c] +
                   xv.y * Ws[(4 * q + 1) * 16 + c] +
                   xv.z * Ws[(4 * q + 2) * 16 + c] +
                   xv.w * Ws[(4 * q + 3) * 16 + c];
        }
        __half hv = __float2half(dinv[node] * acc);
        if (c < 8)
            hlo[(size_t)node * 8 + c] = hv;
        else
            hhi[(size_t)node * 8 + (c - 8)] = hv;
    }
}

// --- CSR gather over a scaled 8-channel fp16 table -----------------------
template <bool L1>
__global__ void k_gather8(const int* __restrict__ rp,
                          const int* __restrict__ adj,
                          const float* __restrict__ dinv,
                          const __half* __restrict__ hs,
                          const float* __restrict__ bias, int ch0,
                          void* __restrict__ o, int n) {
    long long total = (long long)n * 8;
    long long i = (long long)blockIdx.x * blockDim.x + threadIdx.x;
    long long stride = (long long)gridDim.x * blockDim.x;
    for (; i < total; i += stride) {
        int v = (int)(i >> 3);
        int j = (int)(i & 7);
        int start = (v == 0) ? 0 : rp[v - 1];
        int end = rp[v];
        float a0 = 0.f, a1 = 0.f, a2 = 0.f, a3 = 0.f;
        int k = start;
        for (; k + 3 < end; k += 4) {
            int s0 = adj[k], s1 = adj[k + 1], s2 = adj[k + 2], s3 = adj[k + 3];
            a0 += __half2float(hs[(size_t)s0 * 8 + j]);
            a1 += __half2float(hs[(size_t)s1 * 8 + j]);
            a2 += __half2float(hs[(size_t)s2 * 8 + j]);
            a3 += __half2float(hs[(size_t)s3 * 8 + j]);
        }
        for (; k < end; ++k) a0 += __half2float(hs[(size_t)adj[k] * 8 + j]);
        float dv = dinv[v];
        float val = dv * (((a0 + a1) + (a2 + a3)) + __half2float(hs[i]));
        if (L1) {
            val = fmaxf(val + bias[ch0 + j], 0.f);
            ((__half*)o)[i] = __float2half(dv * val);
        } else {
            ((float*)o)[i] = val;
        }
    }
}

// --- out = [preL|preH] @ W2 + b2 -----------------------------------------
__global__ void k_out(const float* __restrict__ preL,
                      const float* __restrict__ preH,
                      const float* __restrict__ W2,
                      const float* __restrict__ b2, float* __restrict__ out,
                      int n) {
    __shared__ float Ws[16 * 32];
    for (int i = threadIdx.x; i < 16 * 32; i += blockDim.x) Ws[i] = W2[i];
    __syncthreads();
    long long total = (long long)n * 32;
    long long i = (long long)blockIdx.x * blockDim.x + threadIdx.x;
    long long stride = (long long)gridDim.x * blockDim.x;
    for (; i < total; i += stride) {
        int v = (int)(i >> 5);
        int c = (int)(i & 31);
        const float* pl = preL + (size_t)v * 8;
        const float* ph = preH + (size_t)v * 8;
        float acc = b2[c];
#pragma unroll
        for (int j = 0; j < 8; ++j) acc += pl[j] * Ws[j * 32 + c];
#pragma unroll
        for (int j = 0; j < 8; ++j) acc += ph[j] * Ws[(8 + j) * 32 + c];
        out[i] = acc;
    }
}

static inline int blocks_for(long long total) {
    return (int)((total + TPB - 1) / TPB);
}

extern "C" void kernel_launch(void* const* d_in, const int* in_sizes, int n_in,
                              void* d_out, int out_size, void* d_ws,
                              size_t ws_size, hipStream_t stream) {
    const float* x = (const float*)d_in[0];
    const int* ei = (const int*)d_in[1];
    const float* W1 = (const float*)d_in[2];
    const float* b1 = (const float*)d_in[3];
    const float* W2 = (const float*)d_in[4];
    const float* b2 = (const float*)d_in[5];
    float* out = (float*)d_out;

    const int n = in_sizes[0] / 128;  // 200000 nodes
    const int E = in_sizes[1] / 2;    // 6400000 edges
    const int* src = ei;
    const int* dst = ei + E;
    const int nbuck = (n + BUCKN - 1) / BUCKN;  // 196 (<= 256 required)

    // base workspace: dinv n f32 | rp n i32 | adj E i32 | R = E i32 (25.6 MB)
    char* ws = (char*)d_ws;
    float* dinv = (float*)ws;
    int* rp = (int*)(ws + (size_t)n * 4);
    int* adj = (int*)(ws + (size_t)n * 8);
    char* R = ws + (size_t)n * 8 + (size_t)E * 4;
    size_t base_bytes = (size_t)n * 8 + (size_t)E * 8;

    // choose NBB by available scratch (hist = NBB*nbuck*4 after R)
    size_t need1024 = base_bytes + ((size_t)1024 + 33) * nbuck * 4 + 8192;
    const int NBB = (ws_size >= need1024) ? 1024 : 512;
    const int nseg = NBB / SEGROWS;
    const int chunk = (E + NBB - 1) / NBB;

    int* hist = (int*)(R + (size_t)E * 4);
    int* segsum = hist + (size_t)NBB * nbuck;
    int* colsum = segsum + (size_t)nseg * nbuck;
    int* bstart = colsum + nbuck;
    int* bbuf = (int*)R;  // E ints, dead before k_mm1 runs

    // region R after build: h1sL/h1sH/z1sL/z1sH (n*8 half) + preL/preH (n*8 f32)
    __half* h1sL = (__half*)R;
    __half* h1sH = (__half*)(R + (size_t)n * 16);
    __half* z1sL = (__half*)(R + (size_t)n * 32);
    __half* z1sH = (__half*)(R + (size_t)n * 48);
    float* preL = (float*)(R + (size_t)n * 64);
    float* preH = (float*)(R + (size_t)n * 96);

    const int cb = (nbuck + 255) / 256;  // 1

    // --- CSR build (no global atomics) ---
    k_hist<<<NBB, BINT, 0, stream>>>(dst, E, n, nbuck, chunk, hist);
    k_scanA1<<<dim3(cb, nseg), 256, 0, stream>>>(hist, nbuck, segsum);
    k_scanA2<<<cb, 256, 0, stream>>>(segsum, nbuck, nseg, colsum);
    k_scanB<<<1, 256, 0, stream>>>(colsum, nbuck, E, bstart);
    k_scanA3<<<dim3(cb, nseg), 256, 0, stream>>>(hist, nbuck, segsum);
    k_bin<<<NBB, BINT, 0, stream>>>(src, dst, E, n, nbuck, chunk, hist, bstart,
                                    bbuf);
    k_bucket<<<nbuck, 1024, 0, stream>>>(bbuf, bstart, n, rp, dinv, adj);

    // --- layer 1 ---
    k_mm1<<<(n + MMN - 1) / MMN, 512, 0, stream>>>(x, W1, dinv, n, h1sL, h1sH);
    k_gather8<true><<<blocks_for((long long)n * 8), TPB, 0, stream>>>(
        rp, adj, dinv, h1sL, b1, 0, z1sL, n);
    k_gather8<true><<<blocks_for((long long)n * 8), TPB, 0, stream>>>(
        rp, adj, dinv, h1sH, b1, 8, z1sH, n);

    // --- layer 2 ---
    k_gather8<false><<<blocks_for((long long)n * 8), TPB, 0, stream>>>(
        rp, adj, dinv, z1sL, nullptr, 0, preL, n);
    k_gather8<false><<<blocks_for((long long)n * 8), TPB, 0, stream>>>(
        rp, adj, dinv, z1sH, nullptr, 8, preH, n);
    k_out<<<blocks_for((long long)n * 32), TPB, 0, stream>>>(preL, preH, W2, b2,
                                                             out, n);
}

// Round 13
// 380.623 us; speedup vs baseline: 1.4067x; 1.0910x over previous
//
#include <hip/hip_runtime.h>
#include <hip/hip_fp16.h>

// ---------------------------------------------------------------------------
// 2-layer GCN via device-built CSR + L2-resident scaled gather tables.
// CSR build (deterministic two-level counting sort, no global atomics):
//   k_hist -> k_scanA1/A2 (segmented) -> k_scanB -> k_scanA3 -> k_bin ->
//   k_bucket (rp/dinv/adj).  Bucket = 1024 dst nodes (write-window fix).
// NBB=2048 bin/hist blocks (round-12: 1024 blocks = half the device's wave
// slots -> k_bin occupancy 32%, latency-bound at 80 us). 4-way ILP in k_bin.
// Layers (aggregate-first on layer 2; aggregation is linear):
//   h1s = dinv * (x@W1)          fp16 lo/hi 8-ch tables (3.2 MB -> L2-fit)
//   z1s = dinv * relu(agg+b1)    fp16 lo/hi
//   pre = agg(z1s)               f32 lo/hi
//   out = pre @ W2 + b2
// k_mm1 LDS-staged (32-node tiles). Gathers: dinv folded into the table ->
// one random row-read per edge; 8-deep independent accumulators for MLP.
// Region R (E*4 B) = bbuf during build, then {h1s,z1s,pre} exactly.
// ---------------------------------------------------------------------------

#define TPB 256
#define BINT 256
#define SEGROWS 64
#define BUCKSH 10                 // log2(nodes per bucket)
#define BUCKN (1 << BUCKSH)       // 1024 nodes per bucket
#define MMN 32                    // nodes per mm1 tile

__device__ __forceinline__ int clampi(int v, int n) {
    return v < 0 ? 0 : (v >= n ? n - 1 : v);
}

// --- per-block LDS histogram over contiguous edge range ------------------
__global__ __launch_bounds__(BINT) void k_hist(const int* __restrict__ dst,
                                               int E, int n, int nbuck,
                                               int chunk,
                                               int* __restrict__ hist) {
    __shared__ int lh[256];
    const int b = blockIdx.x;
    const int t = threadIdx.x;
    lh[t] = 0;
    __syncthreads();
    const int start = b * chunk;
    const int end = min(E, start + chunk);
    for (int i = start + t; i < end; i += BINT)
        atomicAdd(&lh[clampi(dst[i], n) >> BUCKSH], 1);
    __syncthreads();
    for (int k = t; k < nbuck; k += BINT) hist[b * nbuck + k] = lh[k];
}

// --- segmented column scan stage 1: per-segment column sums --------------
__global__ void k_scanA1(const int* __restrict__ hist, int nbuck,
                         int* __restrict__ segsum) {
    int k = blockIdx.x * blockDim.x + threadIdx.x;
    int seg = blockIdx.y;
    if (k >= nbuck) return;
    const int* row = hist + (size_t)seg * SEGROWS * nbuck + k;
    int sum = 0;
#pragma unroll
    for (int b = 0; b < SEGROWS; ++b) sum += row[(size_t)b * nbuck];
    segsum[seg * nbuck + k] = sum;
}

// --- stage 2: serial scan over segments (nseg <= 32) + colsum ------------
__global__ void k_scanA2(int* __restrict__ segsum, int nbuck, int nseg,
                         int* __restrict__ colsum) {
    int k = blockIdx.x * blockDim.x + threadIdx.x;
    if (k >= nbuck) return;
    int run = 0;
    for (int sg = 0; sg < nseg; ++sg) {
        int v = segsum[sg * nbuck + k];
        segsum[sg * nbuck + k] = run;
        run += v;
    }
    colsum[k] = run;
}

// --- exclusive scan of colsum -> bstart[0..nbuck] ------------------------
__global__ void k_scanB(const int* __restrict__ colsum, int nbuck, int E,
                        int* __restrict__ bstart) {
    __shared__ int s[256];
    const int t = threadIdx.x;
    int loc[4];
    int a = 0;
#pragma unroll
    for (int i = 0; i < 4; ++i) {
        int idx = 4 * t + i;
        loc[i] = (idx < nbuck) ? colsum[idx] : 0;
        a += loc[i];
    }
    s[t] = a;
    __syncthreads();
#pragma unroll
    for (int off = 1; off < 256; off <<= 1) {
        int v = (t >= off) ? s[t - off] : 0;
        __syncthreads();
        s[t] += v;
        __syncthreads();
    }
    int base = s[t] - a;
#pragma unroll
    for (int i = 0; i < 4; ++i) {
        int idx = 4 * t + i;
        if (idx < nbuck) bstart[idx] = base;
        base += loc[i];
    }
    if (t == 255) bstart[nbuck] = E;
}

// --- stage 3: rewrite hist rows to global exclusive prefix ---------------
__global__ void k_scanA3(int* __restrict__ hist, int nbuck,
                         const int* __restrict__ segsum) {
    int k = blockIdx.x * blockDim.x + threadIdx.x;
    int seg = blockIdx.y;
    if (k >= nbuck) return;
    int run = segsum[seg * nbuck + k];
    int* row = hist + (size_t)seg * SEGROWS * nbuck + k;
#pragma unroll
    for (int b = 0; b < SEGROWS; ++b) {
        int v = row[(size_t)b * nbuck];
        row[(size_t)b * nbuck] = run;
        run += v;
    }
}

// --- binning: LDS cursors, LDS atomics only; 4-way ILP -------------------
__global__ __launch_bounds__(BINT) void k_bin(const int* __restrict__ src,
                                              const int* __restrict__ dst,
                                              int E, int n, int nbuck,
                                              int chunk,
                                              const int* __restrict__ hist,
                                              const int* __restrict__ bstart,
                                              int* __restrict__ bbuf) {
    __shared__ int lcur[256];
    const int b = blockIdx.x;
    const int t = threadIdx.x;
    for (int k = t; k < nbuck; k += BINT)
        lcur[k] = bstart[k] + hist[b * nbuck + k];
    __syncthreads();
    const int start = b * chunk;
    const int end = min(E, start + chunk);
    int i = start + t;
    for (; i + 3 * BINT < end; i += 4 * BINT) {
        int s0 = clampi(src[i], n);
        int s1 = clampi(src[i + BINT], n);
        int s2 = clampi(src[i + 2 * BINT], n);
        int s3 = clampi(src[i + 3 * BINT], n);
        int d0 = clampi(dst[i], n);
        int d1 = clampi(dst[i + BINT], n);
        int d2 = clampi(dst[i + 2 * BINT], n);
        int d3 = clampi(dst[i + 3 * BINT], n);
        int p0 = atomicAdd(&lcur[d0 >> BUCKSH], 1);
        int p1 = atomicAdd(&lcur[d1 >> BUCKSH], 1);
        int p2 = atomicAdd(&lcur[d2 >> BUCKSH], 1);
        int p3 = atomicAdd(&lcur[d3 >> BUCKSH], 1);
        bbuf[p0] = ((d0 & (BUCKN - 1)) << 18) | s0;
        bbuf[p1] = ((d1 & (BUCKN - 1)) << 18) | s1;
        bbuf[p2] = ((d2 & (BUCKN - 1)) << 18) | s2;
        bbuf[p3] = ((d3 & (BUCKN - 1)) << 18) | s3;
    }
    for (; i < end; i += BINT) {
        int s0 = clampi(src[i], n);
        int d0 = clampi(dst[i], n);
        int p0 = atomicAdd(&lcur[d0 >> BUCKSH], 1);
        bbuf[p0] = ((d0 & (BUCKN - 1)) << 18) | s0;
    }
}

// --- per-bucket (1024 nodes, 1024 thr): hist -> scan -> rp/dinv -> adj ---
__global__ __launch_bounds__(1024) void k_bucket(const int* __restrict__ bbuf,
                                                 const int* __restrict__ bstart,
                                                 int n, int* __restrict__ rp,
                                                 float* __restrict__ dinv,
                                                 int* __restrict__ adj) {
    __shared__ int lcnt[1024];
    __shared__ int ls[1024];
    const int b = blockIdx.x;
    const int t = threadIdx.x;
    const int start = bstart[b];
    const int end = bstart[b + 1];

    lcnt[t] = 0;
    __syncthreads();
    for (int i = start + t; i < end; i += 1024)
        atomicAdd(&lcnt[((unsigned)bbuf[i]) >> 18], 1);
    __syncthreads();

    int c = lcnt[t];
    ls[t] = c;
    __syncthreads();
#pragma unroll
    for (int off = 1; off < 1024; off <<= 1) {
        int v = (t >= off) ? ls[t - off] : 0;
        __syncthreads();
        ls[t] += v;
        __syncthreads();
    }
    int v = (b << BUCKSH) + t;
    if (v < n) {
        rp[v] = start + ls[t];  // inclusive row end
        dinv[v] = rsqrtf((float)(c + 1));
    }
    int cur0 = start + ls[t] - c;
    __syncthreads();
    lcnt[t] = cur0;  // reuse as write cursor
    __syncthreads();

    for (int i = start + t; i < end; i += 1024) {
        int p = bbuf[i];
        int dl = ((unsigned)p) >> 18;
        int s = p & 0x3FFFF;
        int pos = atomicAdd(&lcnt[dl], 1);
        adj[pos] = s;
    }
}

// --- h1s = dinv*(x@W1): LDS-staged tile (32 nodes), 512 thr --------------
__global__ __launch_bounds__(512) void k_mm1(const float* __restrict__ x,
                                             const float* __restrict__ W,
                                             const float* __restrict__ dinv,
                                             int n, __half* __restrict__ hlo,
                                             __half* __restrict__ hhi) {
    __shared__ float Ws[128 * 16];
    __shared__ float xs[MMN * 132];
    const int t = threadIdx.x;
    for (int i = t; i < 128 * 16; i += 512) Ws[i] = W[i];
    const int node0 = blockIdx.x * MMN;
    {
        const float4* xg = (const float4*)(x + (size_t)node0 * 128);
#pragma unroll
        for (int it = 0; it < 2; ++it) {
            int idx = it * 512 + t;  // float4 index in tile, 0..1023
            int row = idx >> 5;
            int c4 = idx & 31;
            if (node0 + row < n) {
                float4 v = xg[(size_t)row * 32 + c4];
                float* dp = &xs[row * 132 + c4 * 4];
                dp[0] = v.x;
                dp[1] = v.y;
                dp[2] = v.z;
                dp[3] = v.w;
            }
        }
    }
    __syncthreads();
    const int node = node0 + (t >> 4);
    const int c = t & 15;
    if (node < n) {
        const float4* xr4 = (const float4*)&xs[(t >> 4) * 132];
        float acc = 0.f;
#pragma unroll
        for (int q = 0; q < 32; ++q) {
            float4 xv = xr4[q];
            acc += xv.x * Ws[(4 * q + 0) * 16 + c] +
                   xv.y * Ws[(4 * q + 1) * 16 + c] +
                   xv.z * Ws[(4 * q + 2) * 16 + c] +
                   xv.w * Ws[(4 * q + 3) * 16 + c];
        }
        __half hv = __float2half(dinv[node] * acc);
        if (c < 8)
            hlo[(size_t)node * 8 + c] = hv;
        else
            hhi[(size_t)node * 8 + (c - 8)] = hv;
    }
}

// --- CSR gather over a scaled 8-channel fp16 table, 8-deep ILP -----------
template <bool L1>
__global__ void k_gather8(const int* __restrict__ rp,
                          const int* __restrict__ adj,
                          const float* __restrict__ dinv,
                          const __half* __restrict__ hs,
                          const float* __restrict__ bias, int ch0,
                          void* __restrict__ o, int n) {
    long long total = (long long)n * 8;
    long long i = (long long)blockIdx.x * blockDim.x + threadIdx.x;
    long long stride = (long long)gridDim.x * blockDim.x;
    for (; i < total; i += stride) {
        int v = (int)(i >> 3);
        int j = (int)(i & 7);
        int start = (v == 0) ? 0 : rp[v - 1];
        int end = rp[v];
        float a0 = 0.f, a1 = 0.f, a2 = 0.f, a3 = 0.f;
        float a4 = 0.f, a5 = 0.f, a6 = 0.f, a7 = 0.f;
        int k = start;
        for (; k + 7 < end; k += 8) {
            int s0 = adj[k], s1 = adj[k + 1], s2 = adj[k + 2], s3 = adj[k + 3];
            int s4 = adj[k + 4], s5 = adj[k + 5], s6 = adj[k + 6],
                s7 = adj[k + 7];
            a0 += __half2float(hs[(size_t)s0 * 8 + j]);
            a1 += __half2float(hs[(size_t)s1 * 8 + j]);
            a2 += __half2float(hs[(size_t)s2 * 8 + j]);
            a3 += __half2float(hs[(size_t)s3 * 8 + j]);
            a4 += __half2float(hs[(size_t)s4 * 8 + j]);
            a5 += __half2float(hs[(size_t)s5 * 8 + j]);
            a6 += __half2float(hs[(size_t)s6 * 8 + j]);
            a7 += __half2float(hs[(size_t)s7 * 8 + j]);
        }
        for (; k < end; ++k) a0 += __half2float(hs[(size_t)adj[k] * 8 + j]);
        float dv = dinv[v];
        float val =
            dv * ((((a0 + a1) + (a2 + a3)) + ((a4 + a5) + (a6 + a7))) +
                  __half2float(hs[i]));
        if (L1) {
            val = fmaxf(val + bias[ch0 + j], 0.f);
            ((__half*)o)[i] = __float2half(dv * val);
        } else {
            ((float*)o)[i] = val;
        }
    }
}

// --- out = [preL|preH] @ W2 + b2 -----------------------------------------
__global__ void k_out(const float* __restrict__ preL,
                      const float* __restrict__ preH,
                      const float* __restrict__ W2,
                      const float* __restrict__ b2, float* __restrict__ out,
                      int n) {
    __shared__ float Ws[16 * 32];
    for (int i = threadIdx.x; i < 16 * 32; i += blockDim.x) Ws[i] = W2[i];
    __syncthreads();
    long long total = (long long)n * 32;
    long long i = (long long)blockIdx.x * blockDim.x + threadIdx.x;
    long long stride = (long long)gridDim.x * blockDim.x;
    for (; i < total; i += stride) {
        int v = (int)(i >> 5);
        int c = (int)(i & 31);
        const float* pl = preL + (size_t)v * 8;
        const float* ph = preH + (size_t)v * 8;
        float acc = b2[c];
#pragma unroll
        for (int j = 0; j < 8; ++j) acc += pl[j] * Ws[j * 32 + c];
#pragma unroll
        for (int j = 0; j < 8; ++j) acc += ph[j] * Ws[(8 + j) * 32 + c];
        out[i] = acc;
    }
}

static inline int blocks_for(long long total) {
    return (int)((total + TPB - 1) / TPB);
}

extern "C" void kernel_launch(void* const* d_in, const int* in_sizes, int n_in,
                              void* d_out, int out_size, void* d_ws,
                              size_t ws_size, hipStream_t stream) {
    const float* x = (const float*)d_in[0];
    const int* ei = (const int*)d_in[1];
    const float* W1 = (const float*)d_in[2];
    const float* b1 = (const float*)d_in[3];
    const float* W2 = (const float*)d_in[4];
    const float* b2 = (const float*)d_in[5];
    float* out = (float*)d_out;

    const int n = in_sizes[0] / 128;  // 200000 nodes
    const int E = in_sizes[1] / 2;    // 6400000 edges
    const int* src = ei;
    const int* dst = ei + E;
    const int nbuck = (n + BUCKN - 1) / BUCKN;  // 196 (<= 256 required)

    // base workspace: dinv n f32 | rp n i32 | adj E i32 | R = E i32 (25.6 MB)
    char* ws = (char*)d_ws;
    float* dinv = (float*)ws;
    int* rp = (int*)(ws + (size_t)n * 4);
    int* adj = (int*)(ws + (size_t)n * 8);
    char* R = ws + (size_t)n * 8 + (size_t)E * 4;
    size_t base_bytes = (size_t)n * 8 + (size_t)E * 8;

    // choose NBB by available scratch (hist = NBB*nbuck*4 after R)
    auto need = [&](int nbb) {
        return base_bytes +
               ((size_t)nbb + (size_t)nbb / SEGROWS + 2) * nbuck * 4 + 8192;
    };
    const int NBB =
        (ws_size >= need(2048)) ? 2048 : ((ws_size >= need(1024)) ? 1024 : 512);
    const int nseg = NBB / SEGROWS;
    const int chunk = (E + NBB - 1) / NBB;

    int* hist = (int*)(R + (size_t)E * 4);
    int* segsum = hist + (size_t)NBB * nbuck;
    int* colsum = segsum + (size_t)nseg * nbuck;
    int* bstart = colsum + nbuck;
    int* bbuf = (int*)R;  // E ints, dead before k_mm1 runs

    // region R after build: h1sL/h1sH/z1sL/z1sH (n*8 half) + preL/preH (n*8 f32)
    __half* h1sL = (__half*)R;
    __half* h1sH = (__half*)(R + (size_t)n * 16);
    __half* z1sL = (__half*)(R + (size_t)n * 32);
    __half* z1sH = (__half*)(R + (size_t)n * 48);
    float* preL = (float*)(R + (size_t)n * 64);
    float* preH = (float*)(R + (size_t)n * 96);

    const int cb = (nbuck + 255) / 256;  // 1

    // --- CSR build (no global atomics) ---
    k_hist<<<NBB, BINT, 0, stream>>>(dst, E, n, nbuck, chunk, hist);
    k_scanA1<<<dim3(cb, nseg), 256, 0, stream>>>(hist, nbuck, segsum);
    k_scanA2<<<cb, 256, 0, stream>>>(segsum, nbuck, nseg, colsum);
    k_scanB<<<1, 256, 0, stream>>>(colsum, nbuck, E, bstart);
    k_scanA3<<<dim3(cb, nseg), 256, 0, stream>>>(hist, nbuck, segsum);
    k_bin<<<NBB, BINT, 0, stream>>>(src, dst, E, n, nbuck, chunk, hist, bstart,
                                    bbuf);
    k_bucket<<<nbuck, 1024, 0, stream>>>(bbuf, bstart, n, rp, dinv, adj);

    // --- layer 1 ---
    k_mm1<<<(n + MMN - 1) / MMN, 512, 0, stream>>>(x, W1, dinv, n, h1sL, h1sH);
    k_gather8<true><<<blocks_for((long long)n * 8), TPB, 0, stream>>>(
        rp, adj, dinv, h1sL, b1, 0, z1sL, n);
    k_gather8<true><<<blocks_for((long long)n * 8), TPB, 0, stream>>>(
        rp, adj, dinv, h1sH, b1, 8, z1sH, n);

    // --- layer 2 ---
    k_gather8<false><<<blocks_for((long long)n * 8), TPB, 0, stream>>>(
        rp, adj, dinv, z1sL, nullptr, 0, preL, n);
    k_gather8<false><<<blocks_for((long long)n * 8), TPB, 0, stream>>>(
        rp, adj, dinv, z1sH, nullptr, 8, preH, n);
    k_out<<<blocks_for((long long)n * 32), TPB, 0, stream>>>(preL, preH, W2, b2,
                                                             out, n);
}